// Round 8
// baseline (5458.935 us; speedup 1.0000x reference)
//
#include <hip/hip_runtime.h>
#include <math.h>

// Problem constants (reference: BS=32, N=M=1024, eps=0.1, 200 iters)
#define BS    32
#define N     1024
#define M     1024
#define ITERS 200

// 8 WGs per batch, 512 threads -> grid 256 = 1 WG/CU.
// G on-chip per WG (256 KB): rows [0,64) in VGPRs (64 regs/lane payload),
// rows [64,128) in LDS (128 KB). Iteration sweep touches NO global memory.
// Minimal sync structure (R4 skeleton): 4 __syncthreads + one 8-wide
// inter-WG barrier per iteration. No early exit (it never fires: Sinkhorn
// contraction ~0.987/iter leaves ~7% residual at t=200; fp32 fixed point
// is never reached).
#define WPB   8
#define ROWS  (N / WPB)      // 128 rows per WG
#define T     512            // 8 waves
#define NW    8
#define RREG  8              // register rows per wave
#define RLDS  8              // LDS rows per wave

// ws: counters + double-buffered column partials [2][BS][WPB][M] (2 MB)
#define CNT_BYTES  4096
#define PART_OFF   ((size_t)CNT_BYTES)
#define PART_BYTES ((size_t)2 * BS * WPB * M * 4)
#define WS_NEEDED  (PART_OFF + PART_BYTES)

// unpack two u16 from a 32-bit word to floats (raw, unscaled)
__device__ __forceinline__ float2 upair(unsigned w) {
    return make_float2((float)(w & 0xffffu), (float)(w >> 16));
}

// Ghat = round(65535 * exp(-10*C)); the 1/65535 scales cancel algebraically:
//   u' = MU/(Ghat.v) == u/65535 ; col = sum u'*Ghat == u^T G ;
//   Gamma*n = u' * Ghat * v * N
__device__ __forceinline__ unsigned qq(float c0, float c1) {
    const float KE = -14.4269504088896340f;   // -10*log2(e)
    unsigned a = __float2uint_rn(65535.0f * __builtin_amdgcn_exp2f(KE * c0));
    unsigned b = __float2uint_rn(65535.0f * __builtin_amdgcn_exp2f(KE * c1));
    return a | (b << 16);
}

__global__ __launch_bounds__(T) void sinkhorn_v8(
    const float* __restrict__ C,
    float* __restrict__ Gout,            // d_out: final Gamma*n only
    unsigned* __restrict__ cnt,          // [BS] stride-32 uints
    float* __restrict__ partials)        // [2][BS][WPB][M]
{
    const int bid  = blockIdx.x;
    const int b    = bid & (BS - 1);   // all 8 WGs of a batch: bid%8 == b%8
    const int k    = bid >> 5;         // 0..7  (-> co-located on one XCD)
    const int tid  = threadIdx.x;
    const int lane = tid & 63;
    const int wave = tid >> 6;

    const size_t sl = ((size_t)b * N + (size_t)k * ROWS) * M;
    const float MU = 1.0f / (float)N;
    const float NU = 1.0f / (float)M;

    // LDS: 131072 (G rows 64..127) + 16384 (combine) + 4096 (v) = 148 KB
    __shared__ uint4 Glds[NW * RLDS][M / 8];
    __shared__ float part4[4][M];
    __shared__ float v_lds[M];

    // Register payload: 8 rows x 2 uint4 = 64 VGPRs per lane.
    // Per row, lane covers cols {4l..4l+3},{256+4l..},{512+4l..},{768+4l..}.
    uint4 qA[RREG], qB[RREG];

    // ---- prologue: quantize own 128 rows (64 -> regs, 64 -> LDS) ----
    #pragma unroll
    for (int i = 0; i < RREG; ++i) {
        const int row = wave * RREG + i;
        const float4* cr = (const float4*)(C + sl + (size_t)row * M);
        float4 a0 = cr[lane],       a1 = cr[64 + lane];
        float4 b0 = cr[128 + lane], b1 = cr[192 + lane];
        qA[i].x = qq(a0.x, a0.y);  qA[i].y = qq(a0.z, a0.w);
        qA[i].z = qq(a1.x, a1.y);  qA[i].w = qq(a1.z, a1.w);
        qB[i].x = qq(b0.x, b0.y);  qB[i].y = qq(b0.z, b0.w);
        qB[i].z = qq(b1.x, b1.y);  qB[i].w = qq(b1.z, b1.w);
    }
    #pragma unroll
    for (int j = 0; j < RLDS; ++j) {
        const int row = 64 + wave * RLDS + j;
        const float4* cr = (const float4*)(C + sl + (size_t)row * M);
        float4 a0 = cr[lane],       a1 = cr[64 + lane];
        float4 b0 = cr[128 + lane], b1 = cr[192 + lane];
        uint4 oa, ob;
        oa.x = qq(a0.x, a0.y);  oa.y = qq(a0.z, a0.w);
        oa.z = qq(a1.x, a1.y);  oa.w = qq(a1.z, a1.w);
        ob.x = qq(b0.x, b0.y);  ob.y = qq(b0.z, b0.w);
        ob.z = qq(b1.x, b1.y);  ob.w = qq(b1.z, b1.w);
        Glds[wave * RLDS + j][lane]      = oa;
        Glds[wave * RLDS + j][64 + lane] = ob;
    }
    ((float2*)v_lds)[tid] = make_float2(NU, NU);
    __syncthreads();

    unsigned* mycnt = cnt + b * 32;
    const float4* v4 = (const float4*)v_lds;
    float4 vra0 = v4[lane],       vra1 = v4[64 + lane],
           vrb0 = v4[128 + lane], vrb1 = v4[192 + lane];

    float ureg[RREG + RLDS];   // u for own 16 rows, all lanes (static idx)

    for (int t = 0; t < ITERS; ++t) {
        const int par = t & 1;
        float4 ca0 = make_float4(0,0,0,0), ca1 = make_float4(0,0,0,0),
               cb0 = make_float4(0,0,0,0), cb1 = make_float4(0,0,0,0);

        auto dorow = [&](uint4 qa, uint4 qb) -> float {
            float2 g0 = upair(qa.x), g1 = upair(qa.y),
                   g2 = upair(qa.z), g3 = upair(qa.w);
            float2 h0 = upair(qb.x), h1 = upair(qb.y),
                   h2 = upair(qb.z), h3 = upair(qb.w);
            float pa = (g0.x*vra0.x + g0.y*vra0.y) + (g1.x*vra0.z + g1.y*vra0.w);
            float pb = (g2.x*vra1.x + g2.y*vra1.y) + (g3.x*vra1.z + g3.y*vra1.w);
            float pc = (h0.x*vrb0.x + h0.y*vrb0.y) + (h1.x*vrb0.z + h1.y*vrb0.w);
            float pd = (h2.x*vrb1.x + h2.y*vrb1.y) + (h3.x*vrb1.z + h3.y*vrb1.w);
            float dot = (pa + pb) + (pc + pd);
            #pragma unroll
            for (int off = 32; off > 0; off >>= 1)
                dot += __shfl_xor(dot, off, 64);
            float ui = MU / dot;     // identical in all 64 lanes
            ca0.x += ui*g0.x; ca0.y += ui*g0.y; ca0.z += ui*g1.x; ca0.w += ui*g1.y;
            ca1.x += ui*g2.x; ca1.y += ui*g2.y; ca1.z += ui*g3.x; ca1.w += ui*g3.y;
            cb0.x += ui*h0.x; cb0.y += ui*h0.y; cb0.z += ui*h1.x; cb0.w += ui*h1.y;
            cb1.x += ui*h2.x; cb1.y += ui*h2.y; cb1.z += ui*h3.x; cb1.w += ui*h3.y;
            return ui;
        };

        // ---- fused sweep: 8 reg rows + 8 LDS rows per wave ----
        #pragma unroll
        for (int i = 0; i < RREG; ++i) {
            uint4 la = Glds[wave * RLDS + i][lane];       // issue LDS reads
            uint4 lb = Glds[wave * RLDS + i][64 + lane];  // early
            ureg[i]        = dorow(qA[i], qB[i]);
            ureg[RREG + i] = dorow(la, lb);
        }

        // ---- combine 8 waves in part4[4][M], 2 syncs, no divergence tree --
        if (wave < 4) {
            float4* p4 = (float4*)part4[wave];
            p4[lane]       = ca0;
            p4[64 + lane]  = ca1;
            p4[128 + lane] = cb0;
            p4[192 + lane] = cb1;
        }
        __syncthreads();
        if (wave >= 4) {   // exclusive slot ownership: deterministic RMW
            float4* p4 = (float4*)part4[wave - 4];
            float4 x0 = p4[lane], x1 = p4[64+lane],
                   x2 = p4[128+lane], x3 = p4[192+lane];
            x0.x += ca0.x; x0.y += ca0.y; x0.z += ca0.z; x0.w += ca0.w;
            x1.x += ca1.x; x1.y += ca1.y; x1.z += ca1.z; x1.w += ca1.w;
            x2.x += cb0.x; x2.y += cb0.y; x2.z += cb0.z; x2.w += cb0.w;
            x3.x += cb1.x; x3.y += cb1.y; x3.z += cb1.z; x3.w += cb1.w;
            p4[lane] = x0; p4[64+lane] = x1; p4[128+lane] = x2; p4[192+lane] = x3;
        }
        __syncthreads();
        // all 512 threads: sum 4 slots, write WG partial (coalesced float2)
        {
            const float2* q0 = (const float2*)part4[0];
            const float2* q1 = (const float2*)part4[1];
            const float2* q2 = (const float2*)part4[2];
            const float2* q3 = (const float2*)part4[3];
            float2 s0 = q0[tid], s1 = q1[tid], s2 = q2[tid], s3 = q3[tid];
            float2 s;
            s.x = (s0.x + s1.x) + (s2.x + s3.x);
            s.y = (s0.y + s1.y) + (s2.y + s3.y);
            float2* pg = (float2*)(partials +
                (((size_t)par * BS + b) * WPB + k) * M);
            pg[tid] = s;
        }
        __syncthreads();   // drains stores (vmcnt0) before the release
        // ---- single 8-wide inter-WG barrier for this batch ----
        if (tid == 0) {
            __hip_atomic_fetch_add(mycnt, 1u, __ATOMIC_RELEASE,
                                   __HIP_MEMORY_SCOPE_AGENT);
            const unsigned tgt = (unsigned)WPB * (unsigned)(t + 1);
            while (__hip_atomic_load(mycnt, __ATOMIC_ACQUIRE,
                                     __HIP_MEMORY_SCOPE_AGENT) < tgt)
                __builtin_amdgcn_s_sleep(1);
        }
        __syncthreads();
        // ---- v = NU / sum_p partial[p]  (fixed order, all threads) ----
        {
            const float2* pall = (const float2*)(partials +
                ((size_t)par * BS + b) * ((size_t)WPB * M));
            float2 s0 = pall[tid];
            float2 s1 = pall[(size_t)1*(M/2) + tid];
            float2 s2 = pall[(size_t)2*(M/2) + tid];
            float2 s3 = pall[(size_t)3*(M/2) + tid];
            float2 s4 = pall[(size_t)4*(M/2) + tid];
            float2 s5 = pall[(size_t)5*(M/2) + tid];
            float2 s6 = pall[(size_t)6*(M/2) + tid];
            float2 s7 = pall[(size_t)7*(M/2) + tid];
            float sx = ((s0.x+s1.x)+(s2.x+s3.x)) + ((s4.x+s5.x)+(s6.x+s7.x));
            float sy = ((s0.y+s1.y)+(s2.y+s3.y)) + ((s4.y+s5.y)+(s6.y+s7.y));
            ((float2*)v_lds)[tid] = make_float2(NU / sx, NU / sy);
        }
        __syncthreads();
        vra0 = v4[lane];       vra1 = v4[64 + lane];
        vrb0 = v4[128 + lane]; vrb1 = v4[192 + lane];
    }

    // ---- epilogue: Gamma*n = u' * Ghat * v * N (scales cancel) ----
    const float nN = (float)N;
    auto emit = [&](float* rowp, uint4 qa, uint4 qb, float un) {
        float2 g0 = upair(qa.x), g1 = upair(qa.y),
               g2 = upair(qa.z), g3 = upair(qa.w);
        float2 h0 = upair(qb.x), h1 = upair(qb.y),
               h2 = upair(qb.z), h3 = upair(qb.w);
        float4* o4 = (float4*)rowp;
        o4[lane]       = make_float4(un*g0.x*vra0.x, un*g0.y*vra0.y,
                                     un*g1.x*vra0.z, un*g1.y*vra0.w);
        o4[64 + lane]  = make_float4(un*g2.x*vra1.x, un*g2.y*vra1.y,
                                     un*g3.x*vra1.z, un*g3.y*vra1.w);
        o4[128 + lane] = make_float4(un*h0.x*vrb0.x, un*h0.y*vrb0.y,
                                     un*h1.x*vrb0.z, un*h1.y*vrb0.w);
        o4[192 + lane] = make_float4(un*h2.x*vrb1.x, un*h2.y*vrb1.y,
                                     un*h3.x*vrb1.z, un*h3.y*vrb1.w);
    };
    #pragma unroll
    for (int i = 0; i < RREG; ++i) {
        const int row = wave * RREG + i;
        emit(Gout + sl + (size_t)row * M, qA[i], qB[i], ureg[i] * nN);
    }
    #pragma unroll
    for (int j = 0; j < RLDS; ++j) {
        const int row = 64 + wave * RLDS + j;
        uint4 la = Glds[wave * RLDS + j][lane];
        uint4 lb = Glds[wave * RLDS + j][64 + lane];
        emit(Gout + sl + (size_t)row * M, la, lb, ureg[RREG + j] * nN);
    }
}

extern "C" void kernel_launch(void* const* d_in, const int* in_sizes, int n_in,
                              void* d_out, int out_size, void* d_ws, size_t ws_size,
                              hipStream_t stream) {
    (void)in_sizes; (void)n_in; (void)out_size;

    const float* C = (const float*)d_in[0];
    float* Gout = (float*)d_out;
    char* ws = (char*)d_ws;

    if (ws_size < WS_NEEDED) return;   // fail loudly (output stays poisoned)

    // Re-zero barrier counters every launch (graph-replay safe).
    hipMemsetAsync(d_ws, 0, CNT_BYTES, stream);

    unsigned* cnt   = (unsigned*)ws;
    float* partials = (float*)(ws + PART_OFF);
    sinkhorn_v8<<<dim3(BS * WPB), dim3(T), 0, stream>>>(
        C, Gout, cnt, partials);
}